// Round 1
// baseline (582.307 us; speedup 1.0000x reference)
//
#include <hip/hip_runtime.h>
#include <math.h>

// NoisyTopKRouter: x[65536,1024] fp32 -> gates[65536,8], aux_loss scalar.
// Memory-bound on reading x (256 MB). Row-per-thread skinny GEMM with
// LDS-transposed, register-pipelined staging; fused top-k/softmax epilogue.

#define N_TOKENS   65536
#define EMBED_DIM  1024
#define NE         8
#define KC         32                 // k-chunk per pipeline stage
#define NC         (EMBED_DIM / KC)   // 32 chunks
#define ROWS       256                // rows per block == threads per block
#define LSTRIDE    36                 // 32 + 4 pad: uniform bank spread, 16B-aligned
#define NOISE_EPS  0.2f

__global__ __launch_bounds__(256)
void router_kernel(const float* __restrict__ x,
                   const float* __restrict__ eps,
                   const float* __restrict__ wg,
                   const float* __restrict__ wn,
                   float* __restrict__ gates,
                   float* __restrict__ acc /* 16 floats: P_sum[8], f_sum[8] */) {
    __shared__ float tile[ROWS * LSTRIDE];   // 36864 B
    __shared__ float blk[16];

    const int t = threadIdx.x;
    const long rowbase = (long)blockIdx.x * ROWS;
    const int srow = t >> 3;          // 0..31: staging row within group
    const int scol = (t & 7) * 4;     // 0..28: staging float4 col
    const float* xg = x + rowbase * EMBED_DIM;

    float4 stage[8];
    // prologue: load chunk 0 into registers (coalesced: 8 lanes cover 128B/row)
#pragma unroll
    for (int m = 0; m < 8; ++m)
        stage[m] = *(const float4*)(xg + (long)(srow + 32 * m) * EMBED_DIM + scol);

    float accg[NE], accn[NE];
#pragma unroll
    for (int e = 0; e < NE; ++e) { accg[e] = 0.f; accn[e] = 0.f; }

    for (int c = 0; c < NC; ++c) {
        // drain staged regs -> LDS (compiler inserts vmcnt wait)
#pragma unroll
        for (int m = 0; m < 8; ++m)
            *(float4*)&tile[(srow + 32 * m) * LSTRIDE + scol] = stage[m];
        __syncthreads();

        // issue next chunk's global loads; they fly during compute below
        if (c + 1 < NC) {
#pragma unroll
            for (int m = 0; m < 8; ++m)
                stage[m] = *(const float4*)(xg + (long)(srow + 32 * m) * EMBED_DIM
                                            + (c + 1) * KC + scol);
        }

        // compute: thread t consumes its own row from LDS; weight index is
        // wave-uniform -> scalar (s_load) path through the K$
        const float* wgc = wg + (long)c * KC * NE;
        const float* wnc = wn + (long)c * KC * NE;
        for (int k = 0; k < KC; k += 4) {
            float4 xv = *(const float4*)&tile[t * LSTRIDE + k];
            float xa[4] = { xv.x, xv.y, xv.z, xv.w };
#pragma unroll
            for (int j = 0; j < 4; ++j) {
#pragma unroll
                for (int e = 0; e < NE; ++e) {
                    accg[e] = fmaf(xa[j], wgc[(k + j) * NE + e], accg[e]);
                    accn[e] = fmaf(xa[j], wnc[(k + j) * NE + e], accn[e]);
                }
            }
        }
        __syncthreads();
    }

    // ---- epilogue: noisy logits, top-2, softmax, gates, aux partials ----
    const float* er = eps + (rowbase + t) * NE;
    float4 ev0 = *(const float4*)(er);
    float4 ev1 = *(const float4*)(er + 4);
    float epsv[NE] = { ev0.x, ev0.y, ev0.z, ev0.w, ev1.x, ev1.y, ev1.z, ev1.w };

    float noisy[NE];
#pragma unroll
    for (int e = 0; e < NE; ++e) {
        float r = accn[e];
        // stable softplus = max(r,0) + log1p(exp(-|r|))  (matches jax.nn.softplus)
        float sp = fmaxf(r, 0.f) + log1pf(expf(-fabsf(r)));
        noisy[e] = accg[e] + (sp + NOISE_EPS) * epsv[e];
    }

    // top-2, lax.top_k tie-break = lowest index first (strict >)
    int i1 = 0; float v1 = noisy[0];
#pragma unroll
    for (int e = 1; e < NE; ++e) if (noisy[e] > v1) { v1 = noisy[e]; i1 = e; }
    int i2 = -1; float v2 = -INFINITY;
#pragma unroll
    for (int e = 0; e < NE; ++e) if (e != i1 && noisy[e] > v2) { v2 = noisy[e]; i2 = e; }

    float b  = expf(v2 - v1);        // <= 1, may underflow to 0 (matches ref)
    float g2 = b / (1.f + b);
    float g1 = 1.f - g2;

    float* gr = gates + (rowbase + t) * NE;
    float ov[NE];
#pragma unroll
    for (int e = 0; e < NE; ++e)
        ov[e] = (e == i1) ? g1 : ((e == i2) ? g2 : 0.f);
    *(float4*)(gr)     = make_float4(ov[0], ov[1], ov[2], ov[3]);
    *(float4*)(gr + 4) = make_float4(ov[4], ov[5], ov[6], ov[7]);

    // aux partials: probs = softmax(clean); f counts gate>0 (g2==0 excluded, like ref)
    float mx = accg[0];
#pragma unroll
    for (int e = 1; e < NE; ++e) mx = fmaxf(mx, accg[e]);
    float p[NE]; float s = 0.f;
#pragma unroll
    for (int e = 0; e < NE; ++e) { p[e] = expf(accg[e] - mx); s += p[e]; }
    float inv = 1.f / s;

    float vals[16];
#pragma unroll
    for (int e = 0; e < NE; ++e) {
        vals[e] = p[e] * inv;
        vals[8 + e] = ((i1 == e) ? 1.f : 0.f) + ((i2 == e && g2 > 0.f) ? 1.f : 0.f);
    }
    // wave-64 butterfly reduce
#pragma unroll
    for (int off = 32; off > 0; off >>= 1)
#pragma unroll
        for (int i = 0; i < 16; ++i)
            vals[i] += __shfl_xor(vals[i], off, 64);

    if (t < 16) blk[t] = 0.f;
    __syncthreads();
    if ((t & 63) == 0) {
#pragma unroll
        for (int i = 0; i < 16; ++i) atomicAdd(&blk[i], vals[i]);
    }
    __syncthreads();
    if (t < 16) atomicAdd(&acc[t], blk[t]);   // device-scope global atomic
}

__global__ void finalize_kernel(const float* __restrict__ acc,
                                float* __restrict__ out_aux) {
    if (threadIdx.x == 0 && blockIdx.x == 0) {
        const float invn = 1.f / (float)N_TOKENS;
        float aux = 0.f;
#pragma unroll
        for (int e = 0; e < NE; ++e)
            aux += (acc[e] * invn) * (acc[8 + e] * invn);
        *out_aux = (float)NE * aux;
    }
}

extern "C" void kernel_launch(void* const* d_in, const int* in_sizes, int n_in,
                              void* d_out, int out_size, void* d_ws, size_t ws_size,
                              hipStream_t stream) {
    const float* x   = (const float*)d_in[0];
    const float* eps = (const float*)d_in[1];
    const float* wg  = (const float*)d_in[2];
    const float* wn  = (const float*)d_in[3];
    float* out = (float*)d_out;
    float* acc = (float*)d_ws;

    // ws is poisoned 0xAA before every timed launch: zero the 16 accumulators
    hipMemsetAsync(d_ws, 0, 16 * sizeof(float), stream);

    router_kernel<<<dim3(N_TOKENS / ROWS), dim3(ROWS), 0, stream>>>(
        x, eps, wg, wn, out, acc);
    // aux_loss is the last element of the concatenated output
    finalize_kernel<<<dim3(1), dim3(64), 0, stream>>>(acc, out + (out_size - 1));
}

// Round 2
// 581.012 us; speedup vs baseline: 1.0022x; 1.0022x over previous
//
#include <hip/hip_runtime.h>
#include <math.h>

// NoisyTopKRouter: x[65536,1024] fp32 -> gates[65536,8] + aux_loss.
// Memory-bound (x = 256 MB). Design R2:
//  - block = 256 thr = 4 waves, covers 64 rows; wave w owns K-range [256w, 256w+256)
//    -> grid 1024 blocks = 4 blocks/CU = 16 waves/CU (was 1 block/CU in R1).
//  - no LDS staging of x: lane streams its own row with float4 loads (sector
//    requests to the same 128B line merge in L1/L2; HBM traffic stays 1x).
//  - no barriers in the K loop; single combine barrier at the end (waves 1-3
//    dump 16 partials to LDS, wave 0 sums + runs the fused epilogue).
//  - only 4 float4 live per iteration + 16 accs: no spill even at tight VGPR
//    budgets (R1 spilled 75 MB of scratch at VGPR_Count=52).

#define N_TOKENS   65536
#define EMBED_DIM  1024
#define NE         8
#define BROWS      64                  // rows per block
#define KW         256                 // K-range per wave
#define NOISE_EPS  0.2f

__global__ __launch_bounds__(256, 4)
void router_kernel(const float* __restrict__ x,
                   const float* __restrict__ eps,
                   const float* __restrict__ wg,
                   const float* __restrict__ wn,
                   float* __restrict__ gates,
                   float* __restrict__ acc /* 16 floats: P_sum[8], f_sum[8] */) {
    __shared__ float part[3][BROWS][16];   // waves 1..3 partials, 12 KB

    const int t = threadIdx.x;
    const int lane = t & 63;
    const int w = __builtin_amdgcn_readfirstlane(t >> 6);   // wave id, scalar
    const long rowbase = (long)blockIdx.x * BROWS;
    const long row = rowbase + lane;

    const float* xr  = x + row * EMBED_DIM + w * KW;   // this wave's K slice
    const float* wgw = wg + (long)w * KW * NE;         // scalar base (w uniform)
    const float* wnw = wn + (long)w * KW * NE;

    float accg[NE], accn[NE];
#pragma unroll
    for (int e = 0; e < NE; ++e) { accg[e] = 0.f; accn[e] = 0.f; }

    // 16 chunks x 16 k. 4 float4 loads in flight per iter; weights via s_load.
#pragma unroll 1
    for (int c = 0; c < KW / 16; ++c) {
        float4 xv[4];
#pragma unroll
        for (int j = 0; j < 4; ++j)
            xv[j] = *(const float4*)(xr + c * 16 + j * 4);
        const float* wgc = wgw + c * 16 * NE;
        const float* wnc = wnw + c * 16 * NE;
#pragma unroll
        for (int j = 0; j < 4; ++j) {
            float xa[4] = { xv[j].x, xv[j].y, xv[j].z, xv[j].w };
#pragma unroll
            for (int q = 0; q < 4; ++q) {
                const int k = j * 4 + q;
#pragma unroll
                for (int e = 0; e < NE; ++e) {
                    accg[e] = fmaf(xa[q], wgc[k * NE + e], accg[e]);
                    accn[e] = fmaf(xa[q], wnc[k * NE + e], accn[e]);
                }
            }
        }
    }

    // ---- combine the 4-way K split ----
    if (w != 0) {
#pragma unroll
        for (int e = 0; e < NE; ++e) {
            part[w - 1][lane][e]      = accg[e];
            part[w - 1][lane][NE + e] = accn[e];
        }
    }
    __syncthreads();
    if (w != 0) return;

#pragma unroll
    for (int v = 0; v < 3; ++v)
#pragma unroll
        for (int e = 0; e < NE; ++e) {
            accg[e] += part[v][lane][e];
            accn[e] += part[v][lane][NE + e];
        }

    // ---- fused epilogue (wave 0, one row per lane) ----
    const float* er = eps + row * NE;
    float4 ev0 = *(const float4*)(er);
    float4 ev1 = *(const float4*)(er + 4);
    float epsv[NE] = { ev0.x, ev0.y, ev0.z, ev0.w, ev1.x, ev1.y, ev1.z, ev1.w };

    float noisy[NE];
#pragma unroll
    for (int e = 0; e < NE; ++e) {
        float r = accn[e];
        float sp = fmaxf(r, 0.f) + log1pf(expf(-fabsf(r)));   // stable softplus
        noisy[e] = accg[e] + (sp + NOISE_EPS) * epsv[e];
    }

    // top-2, lax.top_k tie-break = lowest index (strict >)
    int i1 = 0; float v1 = noisy[0];
#pragma unroll
    for (int e = 1; e < NE; ++e) if (noisy[e] > v1) { v1 = noisy[e]; i1 = e; }
    int i2 = -1; float v2 = -INFINITY;
#pragma unroll
    for (int e = 0; e < NE; ++e) if (e != i1 && noisy[e] > v2) { v2 = noisy[e]; i2 = e; }

    float b  = expf(v2 - v1);
    float g2 = b / (1.f + b);
    float g1 = 1.f - g2;

    float* gr = gates + row * NE;
    float ov[NE];
#pragma unroll
    for (int e = 0; e < NE; ++e)
        ov[e] = (e == i1) ? g1 : ((e == i2) ? g2 : 0.f);
    *(float4*)(gr)      = make_float4(ov[0], ov[1], ov[2], ov[3]);
    *(float4*)(gr + 4)  = make_float4(ov[4], ov[5], ov[6], ov[7]);

    // aux partials: P = softmax(clean) mean; f = usage count
    float mx = accg[0];
#pragma unroll
    for (int e = 1; e < NE; ++e) mx = fmaxf(mx, accg[e]);
    float p[NE]; float s = 0.f;
#pragma unroll
    for (int e = 0; e < NE; ++e) { p[e] = expf(accg[e] - mx); s += p[e]; }
    float inv = 1.f / s;

    float vals[16];
#pragma unroll
    for (int e = 0; e < NE; ++e) {
        vals[e]      = p[e] * inv;
        vals[NE + e] = ((i1 == e) ? 1.f : 0.f) + ((i2 == e && g2 > 0.f) ? 1.f : 0.f);
    }
#pragma unroll
    for (int off = 32; off > 0; off >>= 1)
#pragma unroll
        for (int i = 0; i < 16; ++i)
            vals[i] += __shfl_xor(vals[i], off, 64);

    if (lane == 0) {
#pragma unroll
        for (int i = 0; i < 16; ++i)
            atomicAdd(&acc[i], vals[i]);   // fire-and-forget, 16/block
    }
}

__global__ void finalize_kernel(const float* __restrict__ acc,
                                float* __restrict__ out_aux) {
    if (threadIdx.x == 0 && blockIdx.x == 0) {
        const float invn = 1.f / (float)N_TOKENS;
        float aux = 0.f;
#pragma unroll
        for (int e = 0; e < NE; ++e)
            aux += (acc[e] * invn) * (acc[NE + e] * invn);
        *out_aux = (float)NE * aux;
    }
}

extern "C" void kernel_launch(void* const* d_in, const int* in_sizes, int n_in,
                              void* d_out, int out_size, void* d_ws, size_t ws_size,
                              hipStream_t stream) {
    const float* x   = (const float*)d_in[0];
    const float* eps = (const float*)d_in[1];
    const float* wg  = (const float*)d_in[2];
    const float* wn  = (const float*)d_in[3];
    float* out = (float*)d_out;
    float* acc = (float*)d_ws;

    hipMemsetAsync(d_ws, 0, 16 * sizeof(float), stream);

    router_kernel<<<dim3(N_TOKENS / BROWS), dim3(256), 0, stream>>>(
        x, eps, wg, wn, out, acc);
    finalize_kernel<<<dim3(1), dim3(64), 0, stream>>>(acc, out + (out_size - 1));
}

// Round 3
// 409.266 us; speedup vs baseline: 1.4228x; 1.4196x over previous
//
#include <hip/hip_runtime.h>
#include <math.h>

// NoisyTopKRouter: x[65536,1024] fp32 -> gates[65536,8] + aux_loss.
// R3: coalesced global->LDS staging via global_load_lds(16B), quad-granule
// padding (1040B stride) so lanes->rows ds_read_b128 hits the 8-words/bank
// floor; k stays wave-uniform so weights ride the scalar K$ path.
// R2 failed at 64 lines/wave-load (address divergence, 560 GB/s); R1 failed
// on VGPR spill (75 MB scratch) -- this design can do neither.

#define N_TOKENS   65536
#define EMBED_DIM  1024
#define NE         8
#define BROWS      64                    // rows per block (= one wave of lanes)
#define CHUNK      64                    // k-cols per chunk
#define NCHUNK     (EMBED_DIM / CHUNK)   // 16
#define QSTRIDE    260                   // floats per 4-row quad (256 + 4 pad)
#define NSLOT      64                    // aux accumulator spreading
#define NOISE_EPS  0.2f

#define AS1(p) (const __attribute__((address_space(1))) void*)(p)
#define AS3(p) (__attribute__((address_space(3))) void*)(p)

__global__ __launch_bounds__(256, 4)
void router_kernel(const float* __restrict__ x,
                   const float* __restrict__ eps,
                   const float* __restrict__ wg,
                   const float* __restrict__ wn,
                   float* __restrict__ gates,
                   float* __restrict__ acc /* NSLOT x 16 floats */) {
    __shared__ float tile[2][16 * QSTRIDE];   // 33280 B; quad q at q*260 floats

    const int t    = threadIdx.x;
    const int lane = t & 63;
    const int w    = __builtin_amdgcn_readfirstlane(t >> 6);   // wave id 0..3
    const long rowbase = (long)blockIdx.x * BROWS;

    // staging map: wave w issues 4 glb_lds, instr i covers quad q=w*4+i
    // (rows 4q..4q+3, cols c*64..+63). lane -> row 4q+(lane>>4), col (lane&15)*4.
    const int srow = lane >> 4;           // 0..3
    const int scol = (lane & 15) * 4;     // 0..60

    // compute map: lane -> row `lane`; float4 base within tile:
    const int tb = (lane >> 2) * QSTRIDE + (lane & 3) * 64 + w * 16;

    float accg[NE], accn[NE];
#pragma unroll
    for (int e = 0; e < NE; ++e) { accg[e] = 0.f; accn[e] = 0.f; }

    // prologue: stage chunk 0 into buf 0
#pragma unroll
    for (int i = 0; i < 4; ++i) {
        const int q = w * 4 + i;
        const float* gp = x + (rowbase + q * 4 + srow) * (long)EMBED_DIM + scol;
        __builtin_amdgcn_global_load_lds(AS1(gp), AS3(&tile[0][q * QSTRIDE]), 16, 0, 0);
    }
    __syncthreads();

#pragma unroll 1
    for (int c = 0; c < NCHUNK; ++c) {
        const int b = c & 1;
        if (c + 1 < NCHUNK) {
#pragma unroll
            for (int i = 0; i < 4; ++i) {
                const int q = w * 4 + i;
                const float* gp = x + (rowbase + q * 4 + srow) * (long)EMBED_DIM
                                  + (c + 1) * CHUNK + scol;
                __builtin_amdgcn_global_load_lds(AS1(gp), AS3(&tile[b ^ 1][q * QSTRIDE]),
                                                 16, 0, 0);
            }
        }

        // wave w consumes k-slice [c*64+16w, c*64+16w+16); weights are
        // wave-uniform -> s_load through the scalar cache
        const float* wgc = wg + ((long)c * CHUNK + w * 16) * NE;
        const float* wnc = wn + ((long)c * CHUNK + w * 16) * NE;
        float4 xv[4];
#pragma unroll
        for (int j = 0; j < 4; ++j)
            xv[j] = *(const float4*)&tile[b][tb + j * 4];
#pragma unroll
        for (int j = 0; j < 4; ++j) {
            const float xa[4] = { xv[j].x, xv[j].y, xv[j].z, xv[j].w };
#pragma unroll
            for (int q = 0; q < 4; ++q) {
                const int k = j * 4 + q;
#pragma unroll
                for (int e = 0; e < NE; ++e) {
                    accg[e] = fmaf(xa[q], wgc[k * NE + e], accg[e]);
                    accn[e] = fmaf(xa[q], wnc[k * NE + e], accn[e]);
                }
            }
        }
        __syncthreads();   // chunk c+1 staged (vmcnt drained) + buf reads done
    }

    // ---- combine 4-way k-split (reuse tile as scratch: 12 KB < 33 KB) ----
    float* part = (float*)tile;
    if (w != 0) {
#pragma unroll
        for (int e = 0; e < NE; ++e) {
            part[((w - 1) * BROWS + lane) * 16 + e]      = accg[e];
            part[((w - 1) * BROWS + lane) * 16 + NE + e] = accn[e];
        }
    }
    __syncthreads();
    if (w != 0) return;

#pragma unroll
    for (int v = 0; v < 3; ++v)
#pragma unroll
        for (int e = 0; e < NE; ++e) {
            accg[e] += part[(v * BROWS + lane) * 16 + e];
            accn[e] += part[(v * BROWS + lane) * 16 + NE + e];
        }

    // ---- fused epilogue (wave 0, one row per lane) — verified in R1/R2 ----
    const long row = rowbase + lane;
    const float* er = eps + row * NE;
    float4 ev0 = *(const float4*)(er);
    float4 ev1 = *(const float4*)(er + 4);
    float epsv[NE] = { ev0.x, ev0.y, ev0.z, ev0.w, ev1.x, ev1.y, ev1.z, ev1.w };

    float noisy[NE];
#pragma unroll
    for (int e = 0; e < NE; ++e) {
        float r = accn[e];
        float sp = fmaxf(r, 0.f) + log1pf(expf(-fabsf(r)));   // stable softplus
        noisy[e] = accg[e] + (sp + NOISE_EPS) * epsv[e];
    }

    int i1 = 0; float v1 = noisy[0];
#pragma unroll
    for (int e = 1; e < NE; ++e) if (noisy[e] > v1) { v1 = noisy[e]; i1 = e; }
    int i2 = -1; float v2 = -INFINITY;
#pragma unroll
    for (int e = 0; e < NE; ++e) if (e != i1 && noisy[e] > v2) { v2 = noisy[e]; i2 = e; }

    float bb = expf(v2 - v1);
    float g2 = bb / (1.f + bb);
    float g1 = 1.f - g2;

    float* gr = gates + row * NE;
    float ov[NE];
#pragma unroll
    for (int e = 0; e < NE; ++e)
        ov[e] = (e == i1) ? g1 : ((e == i2) ? g2 : 0.f);
    *(float4*)(gr)     = make_float4(ov[0], ov[1], ov[2], ov[3]);
    *(float4*)(gr + 4) = make_float4(ov[4], ov[5], ov[6], ov[7]);

    float mx = accg[0];
#pragma unroll
    for (int e = 1; e < NE; ++e) mx = fmaxf(mx, accg[e]);
    float p[NE]; float s = 0.f;
#pragma unroll
    for (int e = 0; e < NE; ++e) { p[e] = expf(accg[e] - mx); s += p[e]; }
    float inv = 1.f / s;

    float vals[16];
#pragma unroll
    for (int e = 0; e < NE; ++e) {
        vals[e]      = p[e] * inv;
        vals[NE + e] = ((i1 == e) ? 1.f : 0.f) + ((i2 == e && g2 > 0.f) ? 1.f : 0.f);
    }
#pragma unroll
    for (int off = 32; off > 0; off >>= 1)
#pragma unroll
        for (int i = 0; i < 16; ++i)
            vals[i] += __shfl_xor(vals[i], off, 64);

    if (lane == 0) {
        float* slot = acc + (blockIdx.x & (NSLOT - 1)) * 16;
#pragma unroll
        for (int i = 0; i < 16; ++i)
            atomicAdd(&slot[i], vals[i]);
    }
}

__global__ void finalize_kernel(const float* __restrict__ acc,
                                float* __restrict__ out_aux) {
    __shared__ float s[16];
    const int t = threadIdx.x;
    if (t < 16) {
        float v = 0.f;
        for (int j = 0; j < NSLOT; ++j) v += acc[j * 16 + t];
        s[t] = v;
    }
    __syncthreads();
    if (t == 0) {
        const float invn = 1.f / (float)N_TOKENS;
        float aux = 0.f;
#pragma unroll
        for (int e = 0; e < NE; ++e)
            aux += (s[e] * invn) * (s[NE + e] * invn);
        *out_aux = (float)NE * aux;
    }
}

extern "C" void kernel_launch(void* const* d_in, const int* in_sizes, int n_in,
                              void* d_out, int out_size, void* d_ws, size_t ws_size,
                              hipStream_t stream) {
    const float* x   = (const float*)d_in[0];
    const float* eps = (const float*)d_in[1];
    const float* wg  = (const float*)d_in[2];
    const float* wn  = (const float*)d_in[3];
    float* out = (float*)d_out;
    float* acc = (float*)d_ws;

    hipMemsetAsync(d_ws, 0, NSLOT * 16 * sizeof(float), stream);

    router_kernel<<<dim3(N_TOKENS / BROWS), dim3(256), 0, stream>>>(
        x, eps, wg, wn, out, acc);
    finalize_kernel<<<dim3(1), dim3(64), 0, stream>>>(acc, out + (out_size - 1));
}